// Round 1
// baseline (4595.947 us; speedup 1.0000x reference)
//
#include <hip/hip_runtime.h>

#define BB 64
#define CC 128
#define CO 128
#define TTOT 256
#define VV 25
#define SS 3
#define RR 16
#define GG 32
#define EPSV 1e-5f
#define TT 8
#define NCH (TTOT / TT)   // 32

// ---------------- K1: xm = mean over T ----------------
__global__ __launch_bounds__(256) void k_xmean(const float* __restrict__ x,
                                               float* __restrict__ xm) {
    int bc = blockIdx.x;                       // b*C + c
    const float* xp = x + (size_t)bc * (TTOT * VV);
    int t = threadIdx.x;
    float a[VV];
    const float* row = xp + t * VV;
#pragma unroll
    for (int v = 0; v < VV; ++v) a[v] = row[v];
#pragma unroll
    for (int v = 0; v < VV; ++v) {
#pragma unroll
        for (int off = 32; off > 0; off >>= 1) a[v] += __shfl_down(a[v], off, 64);
    }
    __shared__ float sm[4][VV];
    int wave = t >> 6, lane = t & 63;
    if (lane == 0) {
#pragma unroll
        for (int v = 0; v < VV; ++v) sm[wave][v] = a[v];
    }
    __syncthreads();
    if (t < VV) {
        float s = sm[0][t] + sm[1][t] + sm[2][t] + sm[3][t];
        xm[(size_t)bc * VV + t] = s * (1.0f / TTOT);
    }
}

// ---------------- K2: relc = alpha*(Wr @ tanh(q-k) + br) + A ----------------
__global__ __launch_bounds__(256) void k_relc(const float* __restrict__ xm,
    const float* __restrict__ Wq, const float* __restrict__ bq,
    const float* __restrict__ Wk, const float* __restrict__ bk,
    const float* __restrict__ Wr, const float* __restrict__ br,
    const float* __restrict__ A, const float* __restrict__ alpha,
    float* __restrict__ relc) {
    int bs = blockIdx.x;                        // b*S + s
    int b = bs / SS, s = bs % SS;
    int tid = threadIdx.x;
    __shared__ float sxm[CC][VV];               // 12.8 KB
    __shared__ float sq[RR][VV], sk[RR][VV];    // 1.6 KB each
    __shared__ float srel[RR][VV * VV];         // 40 KB

    for (int i = tid; i < CC * VV; i += 256) sxm[i / VV][i % VV] = xm[(size_t)b * CC * VV + i];
    __syncthreads();

    for (int i = tid; i < RR * VV; i += 256) {
        int r = i / VV, u = i % VV;
        const float* wq = Wq + ((size_t)s * RR + r) * CC;
        const float* wk = Wk + ((size_t)s * RR + r) * CC;
        float aq = bq[s * RR + r], ak = bk[s * RR + r];
        for (int c = 0; c < CC; ++c) { float xv = sxm[c][u]; aq += wq[c] * xv; ak += wk[c] * xv; }
        sq[r][u] = aq; sk[r][u] = ak;
    }
    __syncthreads();

    for (int i = tid; i < RR * VV * VV; i += 256) {
        int r = i / (VV * VV), uv = i % (VV * VV);
        srel[r][uv] = tanhf(sq[r][uv / VV] - sk[r][uv % VV]);
    }
    __syncthreads();

    float al = alpha[0];
    for (int i = tid; i < CO * VV * VV; i += 256) {
        int o = i / (VV * VV), uv = i % (VV * VV);
        const float* wr = Wr + ((size_t)s * CO + o) * RR;
        float acc = br[s * CO + o];
#pragma unroll
        for (int r = 0; r < RR; ++r) acc += wr[r] * srel[r][uv];
        relc[((size_t)bs * CO + o) * (VV * VV) + uv] = acc * al + A[(size_t)s * VV * VV + uv];
    }
}

// ---------------- K3: fused v-projection + relc contraction + GN partial stats ----------------
__global__ __launch_bounds__(256) void k_main(const float* __restrict__ x,
    const float* __restrict__ Wv, const float* __restrict__ bv,
    const float* __restrict__ relc, float* __restrict__ outr,
    float* __restrict__ stats) {
    int blk = blockIdx.x;
    int b = blk / NCH, tch = blk % NCH;
    int t0 = tch * TT;
    int tid = threadIdx.x;
    int wave = __builtin_amdgcn_readfirstlane(tid >> 6);
    int lane = tid & 63;

    __shared__ float xt[CC][TT * VV];            // [128][200] = 102.4 KB
    __shared__ float vbuf[4][8][TT * VV];        // 25.6 KB
    __shared__ float gstat[GG][2];

    if (tid < GG) { gstat[tid][0] = 0.f; gstat[tid][1] = 0.f; }

    const float* xb = x + (size_t)b * CC * TTOT * VV;
    for (int i = tid; i < CC * TT * VV; i += 256) {
        int c = i / (TT * VV), col = i % (TT * VV);
        xt[c][col] = xb[(size_t)c * (TTOT * VV) + t0 * VV + col];
    }
    __syncthreads();

    // pairs: pair = lane + p*64 (<200); j = pair/25 = o-slot (0..7), u = pair%25
    for (int pass = 0; pass < 4; ++pass) {
        int obase = pass * 32 + wave * 8;
        float acc[4][TT];
#pragma unroll
        for (int p = 0; p < 4; ++p)
#pragma unroll
            for (int tt = 0; tt < TT; ++tt) acc[p][tt] = 0.f;

        for (int s = 0; s < SS; ++s) {
            // ---- v tile: vbuf[wave][j][col] = sum_c Wv[s,obase+j,c]*xt[c][col] + bv ----
            float v0[8], v1[8], v2[8], v3[8];
#pragma unroll
            for (int j = 0; j < 8; ++j) {
                float bb = bv[s * CO + obase + j];
                v0[j] = bb; v1[j] = bb; v2[j] = bb; v3[j] = bb;
            }
            const float* wvbase = Wv + ((size_t)s * CO + obase) * CC;
#pragma unroll 4
            for (int c = 0; c < CC; ++c) {
                float x0 = xt[c][lane];
                float x1 = xt[c][lane + 64];
                float x2 = xt[c][lane + 128];
                float x3 = (lane < 8) ? xt[c][lane + 192] : 0.f;
#pragma unroll
                for (int j = 0; j < 8; ++j) {
                    float w = wvbase[j * CC + c];
                    v0[j] += w * x0; v1[j] += w * x1; v2[j] += w * x2; v3[j] += w * x3;
                }
            }
#pragma unroll
            for (int j = 0; j < 8; ++j) {
                vbuf[wave][j][lane]       = v0[j];
                vbuf[wave][j][lane + 64]  = v1[j];
                vbuf[wave][j][lane + 128] = v2[j];
                if (lane < 8) vbuf[wave][j][lane + 192] = v3[j];
            }
            __syncthreads();

            // ---- contraction: acc[p][tt] += sum_k relc[b,s,o,u,k] * vbuf[j][tt*25+k] ----
#pragma unroll
            for (int p = 0; p < 4; ++p) {
                int pair = lane + p * 64;
                if (pair < 200) {
                    int j = pair / 25, u = pair % 25;
                    const float* rr = relc + (((size_t)(b * SS + s) * CO) + obase + j) * (VV * VV) + u * VV;
                    float rreg[VV];
#pragma unroll
                    for (int k = 0; k < VV; ++k) rreg[k] = rr[k];
#pragma unroll
                    for (int tt = 0; tt < TT; ++tt) {
                        float a = 0.f;
#pragma unroll
                        for (int k = 0; k < VV; ++k) a += rreg[k] * vbuf[wave][j][tt * VV + k];
                        acc[p][tt] += a;
                    }
                }
            }
            __syncthreads();
        }

        // ---- write raw out + group stats ----
#pragma unroll
        for (int p = 0; p < 4; ++p) {
            int pair = lane + p * 64;
            if (pair < 200) {
                int j = pair / 25, u = pair % 25;
                int o = obase + j;
                float ps = 0.f, pq = 0.f;
                size_t ob = (((size_t)(b * CO + o)) * TTOT + t0) * VV + u;
#pragma unroll
                for (int tt = 0; tt < TT; ++tt) {
                    float val = acc[p][tt];
                    outr[ob + (size_t)tt * VV] = val;
                    ps += val; pq += val * val;
                }
                atomicAdd(&gstat[o >> 2][0], ps);
                atomicAdd(&gstat[o >> 2][1], pq);
            }
        }
    }
    __syncthreads();
    if (tid < GG) {
        atomicAdd(&stats[(b * GG + tid) * 2],     gstat[tid][0]);
        atomicAdd(&stats[(b * GG + tid) * 2 + 1], gstat[tid][1]);
    }
}

// ---------------- K4: GroupNorm apply + residual + ReLU (in place on d_out) ----------------
__global__ __launch_bounds__(256) void k_final(float* __restrict__ out,
    const float* __restrict__ x, const float* __restrict__ stats,
    const float* __restrict__ gw, const float* __restrict__ gb) {
    size_t i = ((size_t)blockIdx.x * 256 + threadIdx.x) * 4;
    int o = (int)((i / (TTOT * VV)) % CO);
    int b = (int)(i / ((size_t)CO * TTOT * VV));
    int g = o >> 2;
    float s0 = stats[(b * GG + g) * 2];
    float s1 = stats[(b * GG + g) * 2 + 1];
    const float inv = 1.0f / (4 * TTOT * VV);   // 25600 elements per group
    float mu = s0 * inv;
    float var = s1 * inv - mu * mu;
    float rs = rsqrtf(var + EPSV) * gw[o];
    float sh = gb[o] - mu * rs;

    float4 r = *(const float4*)(out + i);
    float4 xr = *(const float4*)(x + i);
    float4 res;
    res.x = fmaxf(r.x * rs + sh + xr.x, 0.f);
    res.y = fmaxf(r.y * rs + sh + xr.y, 0.f);
    res.z = fmaxf(r.z * rs + sh + xr.z, 0.f);
    res.w = fmaxf(r.w * rs + sh + xr.w, 0.f);
    *(float4*)(out + i) = res;
}

extern "C" void kernel_launch(void* const* d_in, const int* in_sizes, int n_in,
                              void* d_out, int out_size, void* d_ws, size_t ws_size,
                              hipStream_t stream) {
    const float* x     = (const float*)d_in[0];
    const float* Wq    = (const float*)d_in[1];
    const float* bq    = (const float*)d_in[2];
    const float* Wk    = (const float*)d_in[3];
    const float* bk    = (const float*)d_in[4];
    const float* Wv    = (const float*)d_in[5];
    const float* bv    = (const float*)d_in[6];
    const float* Wr    = (const float*)d_in[7];
    const float* br    = (const float*)d_in[8];
    const float* A     = (const float*)d_in[9];
    const float* alpha = (const float*)d_in[10];
    const float* gw    = (const float*)d_in[11];
    const float* gb    = (const float*)d_in[12];
    float* out = (float*)d_out;

    float* xm    = (float*)d_ws;                      // 204,800 floats
    float* relc  = xm + (size_t)BB * CC * VV;         // 15,360,000 floats
    float* stats = relc + (size_t)BB * SS * CO * VV * VV;  // 4,096 floats

    hipMemsetAsync(stats, 0, (size_t)BB * GG * 2 * sizeof(float), stream);
    k_xmean<<<BB * CC, 256, 0, stream>>>(x, xm);
    k_relc<<<BB * SS, 256, 0, stream>>>(xm, Wq, bq, Wk, bk, Wr, br, A, alpha, relc);
    k_main<<<BB * NCH, 256, 0, stream>>>(x, Wv, bv, relc, out, stats);
    int total = BB * CO * TTOT * VV;                  // 52,428,800
    k_final<<<total / (256 * 4), 256, 0, stream>>>(out, x, stats, gw, gb);
}

// Round 2
// 674.948 us; speedup vs baseline: 6.8093x; 6.8093x over previous
//
#include <hip/hip_runtime.h>

#define BB 64
#define CC 128
#define CO 128
#define TTOT 256
#define VV 25
#define SS 3
#define RR 16
#define GG 32
#define EPSV 1e-5f

typedef __attribute__((ext_vector_type(8))) __bf16 bf16x8;
typedef __attribute__((ext_vector_type(4))) float f32x4;

static __device__ __forceinline__ ushort f2bf(float f) {
    unsigned u = __float_as_uint(f);
    u = (u + 0x7FFF + ((u >> 16) & 1)) >> 16;   // RNE
    return (ushort)u;
}
static __device__ __forceinline__ float bf2f(ushort h) {
    return __uint_as_float(((unsigned)h) << 16);
}
static __device__ __forceinline__ f32x4 mfma16(bf16x8 a, bf16x8 b, f32x4 c) {
    return __builtin_amdgcn_mfma_f32_16x16x32_bf16(a, b, c, 0, 0, 0);
}

// ---------------- K1: xm = mean over T ----------------
__global__ __launch_bounds__(256) void k_xmean(const float* __restrict__ x,
                                               float* __restrict__ xm) {
    int bc = blockIdx.x;
    const float* xp = x + (size_t)bc * (TTOT * VV);
    int t = threadIdx.x;
    float a[VV];
    const float* row = xp + t * VV;
#pragma unroll
    for (int v = 0; v < VV; ++v) a[v] = row[v];
#pragma unroll
    for (int v = 0; v < VV; ++v) {
#pragma unroll
        for (int off = 32; off > 0; off >>= 1) a[v] += __shfl_down(a[v], off, 64);
    }
    __shared__ float sm[4][VV];
    int wave = t >> 6, lane = t & 63;
    if (lane == 0) {
#pragma unroll
        for (int v = 0; v < VV; ++v) sm[wave][v] = a[v];
    }
    __syncthreads();
    if (t < VV) {
        float s = sm[0][t] + sm[1][t] + sm[2][t] + sm[3][t];
        xm[(size_t)bc * VV + t] = s * (1.0f / TTOT);
    }
}

// ---------------- K2: relc = alpha*(Wr @ tanh(q-k) + br) + A ----------------
__global__ __launch_bounds__(256) void k_relc(const float* __restrict__ xm,
    const float* __restrict__ Wq, const float* __restrict__ bq,
    const float* __restrict__ Wk, const float* __restrict__ bk,
    const float* __restrict__ Wr, const float* __restrict__ br,
    const float* __restrict__ A, const float* __restrict__ alpha,
    float* __restrict__ relc) {
    int bs = blockIdx.x;
    int b = bs / SS, s = bs % SS;
    int tid = threadIdx.x;
    __shared__ float sxm[CC][VV];
    __shared__ float sq[RR][VV], sk[RR][VV];
    __shared__ float srel[RR][VV * VV];

    for (int i = tid; i < CC * VV; i += 256) sxm[i / VV][i % VV] = xm[(size_t)b * CC * VV + i];
    __syncthreads();

    for (int i = tid; i < RR * VV; i += 256) {
        int r = i / VV, u = i % VV;
        const float* wq = Wq + ((size_t)s * RR + r) * CC;
        const float* wk = Wk + ((size_t)s * RR + r) * CC;
        float aq = bq[s * RR + r], ak = bk[s * RR + r];
        for (int c = 0; c < CC; ++c) { float xv = sxm[c][u]; aq += wq[c] * xv; ak += wk[c] * xv; }
        sq[r][u] = aq; sk[r][u] = ak;
    }
    __syncthreads();

    for (int i = tid; i < RR * VV * VV; i += 256) {
        int r = i / (VV * VV), uv = i % (VV * VV);
        srel[r][uv] = tanhf(sq[r][uv / VV] - sk[r][uv % VV]);
    }
    __syncthreads();

    float al = alpha[0];
    for (int i = tid; i < CO * VV * VV; i += 256) {
        int o = i / (VV * VV), uv = i % (VV * VV);
        const float* wr = Wr + ((size_t)s * CO + o) * RR;
        float acc = br[s * CO + o];
#pragma unroll
        for (int r = 0; r < RR; ++r) acc += wr[r] * srel[r][uv];
        relc[((size_t)bs * CO + o) * (VV * VV) + uv] = acc * al + A[(size_t)s * VV * VV + uv];
    }
}

// ---------------- K3: fused MFMA v-projection + relc contraction ----------------
// grid: 1024 blocks (b,tchunk), 512 threads (8 waves). TT=16 -> n=400 cols.
// LDS: xt [c8=16][n=400][cc=8] bf16 (102400B) ; Wv [c8=16][264] (8448B) ;
//      v  [o=32][k8=4][t=16][kk=8] bf16 (32768B)
template<bool BFOUT>
__global__ __launch_bounds__(512) void k_main(const float* __restrict__ x,
    const float* __restrict__ Wv, const float* __restrict__ bv,
    const float* __restrict__ relc, ushort* __restrict__ outw,
    float* __restrict__ outf, float* __restrict__ stats) {
    int bid = blockIdx.x;
    int xcd = bid & 7, w8 = bid >> 3;     // group same-b blocks on one XCD
    int b = xcd * 8 + (w8 & 7);
    int tch = w8 >> 3;                    // 0..15
    int tid = threadIdx.x;
    int wvi = tid >> 6;
    int lane = tid & 63;
    int g4 = lane >> 4;
    int l15 = lane & 15;

    __shared__ ushort s_xt[51200];
    __shared__ ushort s_wv[4224];
    __shared__ ushort s_v[16384];
    __shared__ float s_bv[SS * CO];
    __shared__ float s_gstat[GG * 2];

    if (tid < GG * 2) s_gstat[tid] = 0.f;
    if (tid < SS * CO) s_bv[tid] = bv[tid];
    // zero v pad (k=25..31 region: k8==3). GEMM1 only ever writes k<=24 there (kk=0).
    {
        int o = tid >> 4, t = tid & 15;
        *(int4*)&s_v[o * 512 + 3 * 128 + t * 8] = int4{0, 0, 0, 0};
    }

    // ---- stage x tile: lane gathers 8 c's (coalesced per instr) -> one b128 write ----
    const float* xb = x + ((size_t)b * CC) * (TTOT * VV) + tch * 400;
    for (int id = wvi; id < 112; id += 8) {
        int c8 = id / 7, seg = id % 7;
        int n = seg * 64 + lane;
        if (n < 400) {
            float vals[8];
#pragma unroll
            for (int cc = 0; cc < 8; ++cc)
                vals[cc] = xb[(size_t)(c8 * 8 + cc) * (TTOT * VV) + n];
            union { ushort us[8]; int4 v4; } u;
#pragma unroll
            for (int cc = 0; cc < 8; ++cc) u.us[cc] = f2bf(vals[cc]);
            *(int4*)&s_xt[c8 * 3200 + n * 8] = u.v4;
        }
    }
    __syncthreads();

    int mt = wvi & 1;                       // this wave's M-tile in GEMM1

    for (int ob = 0; ob < 4; ++ob) {
        f32x4 acc2[4][2];
#pragma unroll
        for (int oi = 0; oi < 4; ++oi)
#pragma unroll
            for (int ut = 0; ut < 2; ++ut) acc2[oi][ut] = f32x4{0.f, 0.f, 0.f, 0.f};

        for (int s = 0; s < SS; ++s) {
            __syncthreads();   // prev GEMM2 / Wv use complete

            // prefetch relc fragments for GEMM2 (hidden under staging + GEMM1)
            float rf[4][2][8];
#pragma unroll
            for (int oi = 0; oi < 4; ++oi) {
                int ol = wvi * 4 + oi;
                const float* rb = relc + ((size_t)((b * SS + s) * CO) + ob * 32 + ol) * (VV * VV);
#pragma unroll
                for (int ut = 0; ut < 2; ++ut) {
                    int u = ut * 16 + l15;
#pragma unroll
                    for (int j = 0; j < 8; ++j) {
                        int k = g4 * 8 + j;
                        rf[oi][ut][j] = (u < VV && k < VV) ? rb[u * VV + k] : 0.f;
                    }
                }
            }

            // stage Wv slice [32 o][128 c] -> [c8][o][cc]+pad
            {
                const float* wg = Wv + ((size_t)s * CO + ob * 32) * CC;
#pragma unroll
                for (int it = 0; it < 2; ++it) {
                    int f = tid + it * 512;           // 0..1023
                    int o = f >> 5, c4 = f & 31;
                    float4 w4 = *(const float4*)(wg + (size_t)o * CC + c4 * 4);
                    ushort4 h;
                    h.x = f2bf(w4.x); h.y = f2bf(w4.y); h.z = f2bf(w4.z); h.w = f2bf(w4.w);
                    int c8 = c4 >> 1;
                    *(ushort4*)&s_wv[c8 * 264 + o * 8 + (c4 & 1) * 4] = h;
                }
            }
            __syncthreads();   // Wv ready

            // ---- GEMM1: v[32o][400n] = Wv_s @ xt ----
            bf16x8 af[4];
#pragma unroll
            for (int ks = 0; ks < 4; ++ks)
                af[ks] = *(const bf16x8*)&s_wv[(ks * 4 + g4) * 264 + (mt * 16 + l15) * 8];

            for (int nt = (wvi >> 1); nt < 25; nt += 4) {
                f32x4 d = f32x4{0.f, 0.f, 0.f, 0.f};
#pragma unroll
                for (int ks = 0; ks < 4; ++ks) {
                    bf16x8 bf = *(const bf16x8*)&s_xt[(ks * 4 + g4) * 3200 + (nt * 16 + l15) * 8];
                    d = mfma16(af[ks], bf, d);
                }
                int n = nt * 16 + l15;
                int t = n / VV, k = n % VV;
                int vbase = 3 * 0 + (k >> 3) * 128 + t * 8 + (k & 7);
#pragma unroll
                for (int r = 0; r < 4; ++r) {
                    int ol = mt * 16 + g4 * 4 + r;
                    float val = d[r] + s_bv[s * CO + ob * 32 + ol];
                    s_v[ol * 512 + vbase] = f2bf(val);
                }
            }
            __syncthreads();   // v ready

            // ---- GEMM2: acc2[t][u] += v[t][k] * relc[u][k] ----
#pragma unroll
            for (int oi = 0; oi < 4; ++oi) {
                int ol = wvi * 4 + oi;
                bf16x8 av = *(const bf16x8*)&s_v[ol * 512 + g4 * 128 + l15 * 8];
#pragma unroll
                for (int ut = 0; ut < 2; ++ut) {
                    union { ushort us[8]; bf16x8 bf; } bu;
#pragma unroll
                    for (int j = 0; j < 8; ++j) bu.us[j] = f2bf(rf[oi][ut][j]);
                    acc2[oi][ut] = mfma16(av, bu.bf, acc2[oi][ut]);
                }
            }
        }

        // ---- epilogue for this o-block: store + GN partial stats ----
#pragma unroll
        for (int oi = 0; oi < 4; ++oi) {
            int ol = wvi * 4 + oi;
            int o = ob * 32 + ol;
            float ps = 0.f, pq = 0.f;
#pragma unroll
            for (int ut = 0; ut < 2; ++ut) {
                int u = ut * 16 + l15;
                bool uok = (u < VV);
#pragma unroll
                for (int r = 0; r < 4; ++r) {
                    float val = acc2[oi][ut][r];
                    if (uok) {
                        int t = g4 * 4 + r;
                        size_t idx = (((size_t)b * CO + o) * TTOT + tch * 16 + t) * VV + u;
                        if (BFOUT) outw[idx] = f2bf(val);
                        else       outf[idx] = val;
                        ps += val; pq += val * val;
                    }
                }
            }
#pragma unroll
            for (int off = 32; off > 0; off >>= 1) {
                ps += __shfl_down(ps, off, 64);
                pq += __shfl_down(pq, off, 64);
            }
            if (lane == 0) {
                atomicAdd(&s_gstat[(o >> 2) * 2], ps);
                atomicAdd(&s_gstat[(o >> 2) * 2 + 1], pq);
            }
        }
    }
    __syncthreads();
    if (tid < GG * 2) atomicAdd(&stats[b * (GG * 2) + tid], s_gstat[tid]);
}

// ---------------- K4: GroupNorm apply + residual + ReLU ----------------
template<bool BFOUT>
__global__ __launch_bounds__(256) void k_final(float* __restrict__ out,
    const ushort* __restrict__ outw, const float* __restrict__ x,
    const float* __restrict__ stats,
    const float* __restrict__ gw, const float* __restrict__ gb) {
    size_t i = ((size_t)blockIdx.x * 256 + threadIdx.x) * 4;
    int o = (int)((i / (TTOT * VV)) % CO);
    int b = (int)(i / ((size_t)CO * TTOT * VV));
    int g = o >> 2;
    float s0 = stats[b * (GG * 2) + g * 2];
    float s1 = stats[b * (GG * 2) + g * 2 + 1];
    const float inv = 1.0f / (4 * TTOT * VV);
    float mu = s0 * inv;
    float var = s1 * inv - mu * mu;
    float rs = rsqrtf(var + EPSV) * gw[o];
    float sh = gb[o] - mu * rs;

    float4 r;
    if (BFOUT) {
        ushort4 rw = *(const ushort4*)(outw + i);
        r.x = bf2f(rw.x); r.y = bf2f(rw.y); r.z = bf2f(rw.z); r.w = bf2f(rw.w);
    } else {
        r = *(const float4*)(out + i);
    }
    float4 xr = *(const float4*)(x + i);
    float4 res;
    res.x = fmaxf(r.x * rs + sh + xr.x, 0.f);
    res.y = fmaxf(r.y * rs + sh + xr.y, 0.f);
    res.z = fmaxf(r.z * rs + sh + xr.z, 0.f);
    res.w = fmaxf(r.w * rs + sh + xr.w, 0.f);
    *(float4*)(out + i) = res;
}

extern "C" void kernel_launch(void* const* d_in, const int* in_sizes, int n_in,
                              void* d_out, int out_size, void* d_ws, size_t ws_size,
                              hipStream_t stream) {
    const float* x     = (const float*)d_in[0];
    const float* Wq    = (const float*)d_in[1];
    const float* bq    = (const float*)d_in[2];
    const float* Wk    = (const float*)d_in[3];
    const float* bk    = (const float*)d_in[4];
    const float* Wv    = (const float*)d_in[5];
    const float* bv    = (const float*)d_in[6];
    const float* Wr    = (const float*)d_in[7];
    const float* br    = (const float*)d_in[8];
    const float* A     = (const float*)d_in[9];
    const float* alpha = (const float*)d_in[10];
    const float* gw    = (const float*)d_in[11];
    const float* gb    = (const float*)d_in[12];
    float* out = (float*)d_out;

    float* xm    = (float*)d_ws;
    float* relc  = xm + (size_t)BB * CC * VV;
    float* stats = relc + (size_t)BB * SS * CO * VV * VV;
    ushort* outw = (ushort*)(stats + (size_t)BB * GG * 2);
    size_t fixed_bytes = ((size_t)BB * CC * VV + (size_t)BB * SS * CO * VV * VV + (size_t)BB * GG * 2) * 4;
    size_t need = fixed_bytes + (size_t)BB * CO * TTOT * VV * 2;
    bool bfout = (ws_size >= need);

    hipMemsetAsync(stats, 0, (size_t)BB * GG * 2 * sizeof(float), stream);
    k_xmean<<<BB * CC, 256, 0, stream>>>(x, xm);
    k_relc<<<BB * SS, 256, 0, stream>>>(xm, Wq, bq, Wk, bk, Wr, br, A, alpha, relc);
    if (bfout) {
        k_main<true><<<BB * 16, 512, 0, stream>>>(x, Wv, bv, relc, outw, out, stats);
        k_final<true><<<(BB * CO * TTOT * VV) / (256 * 4), 256, 0, stream>>>(out, outw, x, stats, gw, gb);
    } else {
        k_main<false><<<BB * 16, 512, 0, stream>>>(x, Wv, bv, relc, outw, out, stats);
        k_final<false><<<(BB * CO * TTOT * VV) / (256 * 4), 256, 0, stream>>>(out, outw, x, stats, gw, gb);
    }
}

// Round 3
// 407.985 us; speedup vs baseline: 11.2650x; 1.6543x over previous
//
#include <hip/hip_runtime.h>

#define BB 64
#define CC 128
#define CO 128
#define TTOT 256
#define VV 25
#define SS 3
#define RR 16
#define GG 32
#define EPSV 1e-5f
#define TT 8
#define NCOL 200      // TT*VV
#define NCH 32        // TTOT/TT

typedef __attribute__((ext_vector_type(8))) __bf16 bf16x8;
typedef __attribute__((ext_vector_type(4))) float f32x4;

static __device__ __forceinline__ ushort f2bf(float f) {
    unsigned u = __float_as_uint(f);
    u = (u + 0x7FFF + ((u >> 16) & 1)) >> 16;   // RNE
    return (ushort)u;
}
static __device__ __forceinline__ float bf2f(ushort h) {
    return __uint_as_float(((unsigned)h) << 16);
}
static __device__ __forceinline__ f32x4 mfma16(bf16x8 a, bf16x8 b, f32x4 c) {
    return __builtin_amdgcn_mfma_f32_16x16x32_bf16(a, b, c, 0, 0, 0);
}

// ---------------- K1: xm = mean over T ----------------
__global__ __launch_bounds__(256) void k_xmean(const float* __restrict__ x,
                                               float* __restrict__ xm) {
    int bc = blockIdx.x;
    const float* xp = x + (size_t)bc * (TTOT * VV);
    int t = threadIdx.x;
    float a[VV];
    const float* row = xp + t * VV;
#pragma unroll
    for (int v = 0; v < VV; ++v) a[v] = row[v];
#pragma unroll
    for (int v = 0; v < VV; ++v) {
#pragma unroll
        for (int off = 32; off > 0; off >>= 1) a[v] += __shfl_down(a[v], off, 64);
    }
    __shared__ float sm[4][VV];
    int wave = t >> 6, lane = t & 63;
    if (lane == 0) {
#pragma unroll
        for (int v = 0; v < VV; ++v) sm[wave][v] = a[v];
    }
    __syncthreads();
    if (t < VV) {
        float s = sm[0][t] + sm[1][t] + sm[2][t] + sm[3][t];
        xm[(size_t)bc * VV + t] = s * (1.0f / TTOT);
    }
}

// ---------------- K1b: pack Wv into bf16 MFMA A-fragment order ----------------
// wvp layout: [s][ob(4)][mt(2)][ks(4)][lane(64)][j(8)], value = Wv[s][ob*32+mt*16+(lane&15)][(ks*4+(lane>>4))*8+j]
__global__ __launch_bounds__(512) void k_pack_wv(const float* __restrict__ Wv,
                                                 ushort* __restrict__ wvp) {
    int t = blockIdx.x * 512 + threadIdx.x;      // < 6144
    int lane = t & 63;
    int ks = (t >> 6) & 3;
    int mt = (t >> 8) & 1;
    int ob = (t >> 9) & 3;
    int s  = t >> 11;
    int o  = ob * 32 + mt * 16 + (lane & 15);
    int c0 = (ks * 4 + (lane >> 4)) * 8;
    const float* src = Wv + ((size_t)s * CO + o) * CC + c0;
    float4 a = *(const float4*)src;
    float4 b = *(const float4*)(src + 4);
    union { ushort us[8]; int4 v; } u;
    u.us[0] = f2bf(a.x); u.us[1] = f2bf(a.y); u.us[2] = f2bf(a.z); u.us[3] = f2bf(a.w);
    u.us[4] = f2bf(b.x); u.us[5] = f2bf(b.y); u.us[6] = f2bf(b.z); u.us[7] = f2bf(b.w);
    *(int4*)&wvp[(size_t)t * 8] = u.v;
}

// ---------------- K2: relc -> packed bf16 B-fragment order ----------------
// rp layout per (b,s,o): [ut(2)][g4(4)][l15(16)][j(8)] = 1024 ushorts,
// value = relc[u = ut*16+l15][k = g4*8+j]; pads stay 0 (memset).
__global__ __launch_bounds__(512) void k_relc(const float* __restrict__ xm,
    const float* __restrict__ Wq, const float* __restrict__ bq,
    const float* __restrict__ Wk, const float* __restrict__ bk,
    const float* __restrict__ Wr, const float* __restrict__ br,
    const float* __restrict__ A, const float* __restrict__ alpha,
    ushort* __restrict__ rp) {
    int bs = blockIdx.x;
    int b = bs / SS, s = bs % SS;
    int tid = threadIdx.x;
    __shared__ float sxm[CC * VV];
    __shared__ float sq[RR * VV], sk[RR * VV];
    __shared__ float srel[RR][VV * VV];

    for (int i = tid; i < CC * VV; i += 512) sxm[i] = xm[(size_t)b * CC * VV + i];
    __syncthreads();

    if (tid < RR * VV) {
        int r = tid / VV, u = tid % VV;
        const float* wq = Wq + ((size_t)s * RR + r) * CC;
        const float* wk = Wk + ((size_t)s * RR + r) * CC;
        float aq = bq[s * RR + r], ak = bk[s * RR + r];
        for (int c = 0; c < CC; ++c) { float xv = sxm[c * VV + u]; aq += wq[c] * xv; ak += wk[c] * xv; }
        sq[tid] = aq; sk[tid] = ak;
    }
    __syncthreads();

    for (int i = tid; i < RR * VV * VV; i += 512) {
        int r = i / (VV * VV), uv = i % (VV * VV);
        srel[r][uv] = tanhf(sq[r * VV + uv / VV] - sk[r * VV + uv % VV]);
    }
    __syncthreads();

    float al = alpha[0];
    for (int i = tid; i < CO * VV; i += 512) {
        int o = i / VV, u = i % VV;
        float acc[VV];
        float base = br[s * CO + o];
#pragma unroll
        for (int k = 0; k < VV; ++k) acc[k] = base;
        const float* wr = Wr + ((size_t)s * CO + o) * RR;
#pragma unroll
        for (int r = 0; r < RR; ++r) {
            float w = wr[r];
            const float* sr = &srel[r][u * VV];
#pragma unroll
            for (int k = 0; k < VV; ++k) acc[k] += w * sr[k];
        }
        const float* Ab = A + (size_t)s * VV * VV + u * VV;
        ushort* dst = rp + (size_t)(bs * CO + o) * 1024 + (u >> 4) * 512 + (u & 15) * 8;
#pragma unroll
        for (int kb = 0; kb < 3; ++kb) {
            union { ushort us[8]; int4 v; } pk;
#pragma unroll
            for (int j = 0; j < 8; ++j) pk.us[j] = f2bf(acc[kb * 8 + j] * al + Ab[kb * 8 + j]);
            *(int4*)&dst[kb * 128] = pk.v;
        }
        dst[3 * 128] = f2bf(acc[24] * al + Ab[24]);
    }
}

// ---------------- K3: fused MFMA v-projection + relc contraction ----------------
// grid: 2048 blocks (b, tch of 8 t's), 512 threads (8 waves), 2 blocks/CU.
__global__ __launch_bounds__(512, 4) void k_main(const float* __restrict__ x,
    const ushort* __restrict__ wvp, const float* __restrict__ bv,
    const ushort* __restrict__ rp, ushort* __restrict__ outw,
    float* __restrict__ stats) {
    int bid = blockIdx.x;
    int xcd = bid & 7, g = bid >> 3;
    int b = xcd + 8 * (g >> 5);        // same-b blocks share an XCD -> relc L2-hits
    int tch = g & 31;
    int tid = threadIdx.x;
    int wvi = tid >> 6;
    int lane = tid & 63;
    int g4 = lane >> 4;
    int l15 = lane & 15;

    __shared__ ushort s_xt[16 * 1600];   // [c8][n(200)][cc(8)] bf16, 51.2 KB
    __shared__ ushort s_v[32 * 256];     // [o(32)][k8(4)][t(8)][kk(8)] bf16, 16 KB
    __shared__ float s_bv[SS * CO];
    __shared__ float s_gstat[GG * 2];

    if (tid < GG * 2) s_gstat[tid] = 0.f;
    if (tid < SS * CO) s_bv[tid] = bv[tid];
    if (tid < 256) {  // zero k-pad (k8==3): GEMM1 writes only kk==0 there (k==24)
        int o = tid >> 3, t = tid & 7;
        *(int4*)&s_v[o * 256 + 3 * 64 + t * 8] = int4{0, 0, 0, 0};
    }

    // ---- stage x tile (bf16) ----
    const float* xb = x + ((size_t)b * CC) * (TTOT * VV) + tch * NCOL;
    for (int id = wvi; id < 64; id += 8) {
        int c8 = id >> 2, seg = id & 3;
        int n = seg * 64 + lane;
        if (n < NCOL) {
            float vals[8];
#pragma unroll
            for (int cc = 0; cc < 8; ++cc)
                vals[cc] = xb[(size_t)(c8 * 8 + cc) * (TTOT * VV) + n];
            union { ushort us[8]; int4 v4; } u;
#pragma unroll
            for (int cc = 0; cc < 8; ++cc) u.us[cc] = f2bf(vals[cc]);
            *(int4*)&s_xt[c8 * 1600 + n * 8] = u.v4;
        }
    }

    int mt = wvi & 1;
    int ntbase = wvi >> 1;

    for (int ob = 0; ob < 4; ++ob) {
        f32x4 acc2[4][2];
#pragma unroll
        for (int oi = 0; oi < 4; ++oi)
#pragma unroll
            for (int ut = 0; ut < 2; ++ut) acc2[oi][ut] = f32x4{0.f, 0.f, 0.f, 0.f};

        for (int s = 0; s < SS; ++s) {
            // B-fragments (relc, packed bf16) — issue early, consumed after GEMM1
            bf16x8 bfrag[4][2];
            const ushort* rb = rp + ((size_t)((b * SS + s) * CO) + ob * 32 + wvi * 4) * 1024
                             + g4 * 128 + l15 * 8;
#pragma unroll
            for (int oi = 0; oi < 4; ++oi) {
#pragma unroll
                for (int ut = 0; ut < 2; ++ut)
                    bfrag[oi][ut] = *(const bf16x8*)&rb[oi * 1024 + ut * 512];
            }
            // A-fragments (Wv, packed bf16)
            bf16x8 afrag[4];
            const ushort* wb = wvp + ((size_t)((s * 4 + ob) * 2 + mt) * 4) * 512 + lane * 8;
#pragma unroll
            for (int ks = 0; ks < 4; ++ks)
                afrag[ks] = *(const bf16x8*)&wb[ks * 512];

            float bvr[4];
#pragma unroll
            for (int r = 0; r < 4; ++r)
                bvr[r] = s_bv[s * CO + ob * 32 + mt * 16 + g4 * 4 + r];

            __syncthreads();   // staging done (first iter) / prev GEMM2 s_v reads done

            // ---- GEMM1: v[32o][200n] = Wv_s @ xt ----
            for (int nt = ntbase; nt < 13; nt += 4) {
                f32x4 d = f32x4{0.f, 0.f, 0.f, 0.f};
#pragma unroll
                for (int ks = 0; ks < 4; ++ks) {
                    bf16x8 bf = *(const bf16x8*)&s_xt[(ks * 4 + g4) * 1600 + (nt * 16 + l15) * 8];
                    d = mfma16(afrag[ks], bf, d);
                }
                int n = nt * 16 + l15;
                if (n < NCOL) {
                    int t = n / VV, k = n % VV;
                    int vb = (k >> 3) * 64 + t * 8 + (k & 7);
#pragma unroll
                    for (int r = 0; r < 4; ++r)
                        s_v[(mt * 16 + g4 * 4 + r) * 256 + vb] = f2bf(d[r] + bvr[r]);
                }
            }
            __syncthreads();   // v ready

            // ---- GEMM2: acc2 += v · relc^T ----
#pragma unroll
            for (int oi = 0; oi < 4; ++oi) {
                int ol = wvi * 4 + oi;
                bf16x8 av = *(const bf16x8*)&s_v[ol * 256 + g4 * 64 + (l15 & 7) * 8];
                acc2[oi][0] = mfma16(av, bfrag[oi][0], acc2[oi][0]);
                acc2[oi][1] = mfma16(av, bfrag[oi][1], acc2[oi][1]);
            }
        }

        // ---- epilogue: store + GN partial stats (rows t = g4*4+r valid only for g4<2) ----
#pragma unroll
        for (int oi = 0; oi < 4; ++oi) {
            int o = ob * 32 + wvi * 4 + oi;
            float ps = 0.f, pq = 0.f;
            if (g4 < 2) {
#pragma unroll
                for (int ut = 0; ut < 2; ++ut) {
                    int u = ut * 16 + l15;
                    if (u < VV) {
#pragma unroll
                        for (int r = 0; r < 4; ++r) {
                            float val = acc2[oi][ut][r];
                            int t = g4 * 4 + r;
                            outw[(((size_t)b * CO + o) * TTOT + tch * TT + t) * VV + u] = f2bf(val);
                            ps += val; pq += val * val;
                        }
                    }
                }
            }
#pragma unroll
            for (int off = 32; off > 0; off >>= 1) {
                ps += __shfl_down(ps, off, 64);
                pq += __shfl_down(pq, off, 64);
            }
            if (lane == 0) {
                atomicAdd(&s_gstat[(o >> 2) * 2], ps);
                atomicAdd(&s_gstat[(o >> 2) * 2 + 1], pq);
            }
        }
    }
    __syncthreads();
    if (tid < GG * 2) atomicAdd(&stats[b * (GG * 2) + tid], s_gstat[tid]);
}

// ---------------- K4: GroupNorm apply + residual + ReLU ----------------
__global__ __launch_bounds__(256) void k_final(float* __restrict__ out,
    const ushort* __restrict__ outw, const float* __restrict__ x,
    const float* __restrict__ stats,
    const float* __restrict__ gw, const float* __restrict__ gb) {
    size_t i = ((size_t)blockIdx.x * 256 + threadIdx.x) * 4;
    int o = (int)((i / (TTOT * VV)) % CO);
    int b = (int)(i / ((size_t)CO * TTOT * VV));
    int gg = o >> 2;
    float s0 = stats[b * (GG * 2) + gg * 2];
    float s1 = stats[b * (GG * 2) + gg * 2 + 1];
    const float inv = 1.0f / (4 * TTOT * VV);
    float mu = s0 * inv;
    float var = s1 * inv - mu * mu;
    float rs = rsqrtf(var + EPSV) * gw[o];
    float sh = gb[o] - mu * rs;

    ushort4 rw = *(const ushort4*)(outw + i);
    float4 xr = *(const float4*)(x + i);
    float4 res;
    res.x = fmaxf(bf2f(rw.x) * rs + sh + xr.x, 0.f);
    res.y = fmaxf(bf2f(rw.y) * rs + sh + xr.y, 0.f);
    res.z = fmaxf(bf2f(rw.z) * rs + sh + xr.z, 0.f);
    res.w = fmaxf(bf2f(rw.w) * rs + sh + xr.w, 0.f);
    *(float4*)(out + i) = res;
}

extern "C" void kernel_launch(void* const* d_in, const int* in_sizes, int n_in,
                              void* d_out, int out_size, void* d_ws, size_t ws_size,
                              hipStream_t stream) {
    const float* x     = (const float*)d_in[0];
    const float* Wq    = (const float*)d_in[1];
    const float* bq    = (const float*)d_in[2];
    const float* Wk    = (const float*)d_in[3];
    const float* bk    = (const float*)d_in[4];
    const float* Wv    = (const float*)d_in[5];
    const float* bv    = (const float*)d_in[6];
    const float* Wr    = (const float*)d_in[7];
    const float* br    = (const float*)d_in[8];
    const float* A     = (const float*)d_in[9];
    const float* alpha = (const float*)d_in[10];
    const float* gw    = (const float*)d_in[11];
    const float* gb    = (const float*)d_in[12];
    float* out = (float*)d_out;

    float*  xm    = (float*)d_ws;                               // 204800 f
    float*  stats = xm + (size_t)BB * CC * VV;                  // 4096 f
    ushort* wvp   = (ushort*)(stats + (size_t)BB * GG * 2);     // 49152 us
    ushort* rp    = wvp + 49152;                                // 25,165,824 us
    ushort* outw  = rp + (size_t)BB * SS * CO * 1024;           // 52,428,800 us

    hipMemsetAsync(stats, 0, (size_t)BB * GG * 2 * sizeof(float), stream);
    hipMemsetAsync(rp, 0, (size_t)BB * SS * CO * 1024 * 2, stream);
    k_xmean<<<BB * CC, 256, 0, stream>>>(x, xm);
    k_pack_wv<<<12, 512, 0, stream>>>(Wv, wvp);
    k_relc<<<BB * SS, 512, 0, stream>>>(xm, Wq, bq, Wk, bk, Wr, br, A, alpha, rp);
    k_main<<<2048, 512, 0, stream>>>(x, wvp, bv, rp, outw, stats);
    k_final<<<(BB * CO * TTOT * VV) / (256 * 4), 256, 0, stream>>>(out, outw, x, stats, gw, gb);
}